// Round 8
// baseline (17.068 us; speedup 1.0000x reference)
//
#include <hip/hip_runtime.h>

// Kernel 1: 2048 blocks x 256 threads. Each thread loads 2 CONSECUTIVE items
// (float2/int2, coalesced). A 16-lane row = one 32-item batch (lane q=lane&15
// holds items 2q, 2q+1); wave64 = 4 batches, block = 16 batches.
// Unordered pairs (496 = C(32,2)) enumerated as:
//   - 1 within-lane pair {2q, 2q+1}
//   - lane-distance d=1..7: partner lane's 2 items vs own 2 items (4 slots)
//   - d=8 (antipodal): 4 slots, valid only for (lane&15)<8 (each pair once)
// Partner data moves via DPP row_ror (full-rate VALU, no LDS pipe, no waits);
// direction of rotation is irrelevant for unordered-pair coverage.
// Scores pre-scaled by log2(e); rank (5 bits, 0=invalid) packed into mantissa
// LSBs. sum softplus = ln2*(sum max(y',0) + log2(prod(1+2^-|x'|))).
template<int CTRL>
__device__ __forceinline__ unsigned rowror(unsigned v) {
    return (unsigned)__builtin_amdgcn_update_dpp(0, (int)v, CTRL, 0xF, 0xF, true);
}

__global__ __launch_bounds__(256) void ranknet_partial_kernel(
    const float2* __restrict__ scores2,
    const int2*   __restrict__ rank2,
    const int2*   __restrict__ mask2,
    float2*       __restrict__ partials)
{
    const int gid  = blockIdx.x * 256 + threadIdx.x;
    const int lane = threadIdx.x & 63;
    const int wave = threadIdx.x >> 6;

    const float2 s2 = scores2[gid];
    const int2   r2 = rank2[gid];
    const int2   m2 = mask2[gid];

    const float L2E = 1.4426950408889634f;

    const int rr0 = (m2.x != 0 && r2.x > 0) ? r2.x : 0;
    const int rr1 = (m2.y != 0 && r2.y > 0) ? r2.y : 0;
    const unsigned su0 = (__float_as_uint(s2.x * L2E) & ~31u) | (unsigned)rr0;
    const unsigned su1 = (__float_as_uint(s2.y * L2E) & ~31u) | (unsigned)rr1;
    const float rjnz0 = (rr0 != 0) ? 1.0f : 0.0f;
    const float rjnz1 = (rr1 != 0) ? 1.0f : 0.0f;

    float A = 0.0f;   // sum of max(y',0)          (log2 domain)
    float P = 1.0f;   // prod of (1+2^-|x'|) gated  (<= 2^33, safe)
    float C = 0.0f;   // valid-pair count

    auto slot = [&](unsigned lu, int rjc, float rjnzc, unsigned pu, float gate) {
        const int   ri = (int)(pu & 31u);
        const float x  = __uint_as_float(pu) - __uint_as_float(lu);
        const float y  = (ri < rjc) ? -x : x;            // softplus arg, log2 dom
        const float e  = __builtin_exp2f(-__builtin_fabsf(x));
        const float vf = ((ri != 0) && (ri != rjc)) ? (rjnzc * gate) : 0.0f;
        A  = fmaf(vf, fmaxf(y, 0.0f), A);
        P *= fmaf(vf, e, 1.0f);
        C += vf;
    };

    // within-lane pair {2q, 2q+1}
    slot(su0, rr0, rjnz0, su1, 1.0f);

#define DO_D(D, GATE) {                                   \
        const unsigned pu0 = rowror<0x120 + (D)>(su0);    \
        const unsigned pu1 = rowror<0x120 + (D)>(su1);    \
        slot(su0, rr0, rjnz0, pu0, GATE);                 \
        slot(su0, rr0, rjnz0, pu1, GATE);                 \
        slot(su1, rr1, rjnz1, pu0, GATE);                 \
        slot(su1, rr1, rjnz1, pu1, GATE); }

    DO_D(1, 1.0f)
    DO_D(2, 1.0f)
    DO_D(3, 1.0f)
    DO_D(4, 1.0f)
    DO_D(5, 1.0f)
    DO_D(6, 1.0f)
    DO_D(7, 1.0f)
    const float g8 = ((lane & 15) < 8) ? 1.0f : 0.0f;     // antipodal: count once
    DO_D(8, g8)
#undef DO_D

    // per-lane log, then rotate-reduce across the 16-lane row (DPP, no LDS)
    float v = A + __builtin_log2f(P);
#define ROW_RED(D) {                                                        \
        v += __uint_as_float(rowror<0x120 + (D)>(__float_as_uint(v)));      \
        C += __uint_as_float(rowror<0x120 + (D)>(__float_as_uint(C))); }
    ROW_RED(1) ROW_RED(2) ROW_RED(4) ROW_RED(8)
#undef ROW_RED

    float pb  = (C > 0.0f) ? (v * 0.6931471805599453f) / C : 0.0f;
    float has = (C > 0.0f) ? 1.0f : 0.0f;

    // sum per-batch means across the wave's 4 rows (crosses rows -> shfl)
    pb  += __shfl_xor(pb, 16);  has += __shfl_xor(has, 16);
    pb  += __shfl_xor(pb, 32);  has += __shfl_xor(has, 32);

    __shared__ float2 wpart[4];
    if (lane == 0) wpart[wave] = make_float2(pb, has);
    __syncthreads();
    if (threadIdx.x == 0) {
        float ps = 0.0f, pc = 0.0f;
        #pragma unroll
        for (int w2 = 0; w2 < 4; ++w2) { ps += wpart[w2].x; pc += wpart[w2].y; }
        partials[blockIdx.x] = make_float2(ps, pc);
    }
}

__global__ __launch_bounds__(256) void ranknet_finalize_kernel(
    const float2* __restrict__ partials, int n, float* __restrict__ out)
{
    float s = 0.0f, c = 0.0f;
    for (int i = threadIdx.x; i < n; i += 256) {
        const float2 p = partials[i];
        s += p.x;
        c += p.y;
    }
    #pragma unroll
    for (int off = 32; off > 0; off >>= 1) {
        s += __shfl_xor(s, off);
        c += __shfl_xor(c, off);
    }
    __shared__ float2 wsum[4];
    const int wave = threadIdx.x >> 6;
    const int lane = threadIdx.x & 63;
    if (lane == 0) wsum[wave] = make_float2(s, c);
    __syncthreads();
    if (threadIdx.x == 0) {
        float ts = 0.0f, tc = 0.0f;
        #pragma unroll
        for (int w = 0; w < 4; ++w) { ts += wsum[w].x; tc += wsum[w].y; }
        out[0] = (tc > 0.0f) ? (ts / tc) : 0.0f;
    }
}

extern "C" void kernel_launch(void* const* d_in, const int* in_sizes, int n_in,
                              void* d_out, int out_size, void* d_ws, size_t ws_size,
                              hipStream_t stream) {
    const float2* scores2 = (const float2*)d_in[0];
    const int2*   rank2   = (const int2*)d_in[1];
    const int2*   mask2   = (const int2*)d_in[2];
    float*        out     = (float*)d_out;

    const int total   = in_sizes[0];        // B * 32 = 1,048,576
    const int nblocks = total / 512;        // 2048 blocks, 16 batches each

    float2* partials = (float2*)d_ws;       // 2048 * 8B = 16 KB, every slot written

    ranknet_partial_kernel<<<nblocks, 256, 0, stream>>>(scores2, rank2, mask2, partials);
    ranknet_finalize_kernel<<<1, 256, 0, stream>>>(partials, nblocks, out);
}